// Round 2
// baseline (2378.538 us; speedup 1.0000x reference)
//
#include <hip/hip_runtime.h>

#define NN 256
#define CIN 96
#define COUT 96
#define BB 4

__device__ __forceinline__ float waveReduceSum(float v) {
    #pragma unroll
    for (int m = 32; m >= 1; m >>= 1) v += __shfl_xor(v, m, 64);
    return v;
}

// ---------------- K1: per (b,c) rowsum / colsum / diag / T / S ----------------
__global__ __launch_bounds__(256) void k_aux(const float* __restrict__ X,
                                             float* __restrict__ rows,
                                             float* __restrict__ cols,
                                             float* __restrict__ diag,
                                             float* __restrict__ TSa) {
    const int bc = blockIdx.x;                 // 0..B*C-1
    const float* Xp = X + (size_t)bc * NN * NN;
    const int tid = threadIdx.x;
    const int wave = tid >> 6, lane = tid & 63;

    __shared__ float rowsL[NN];
    __shared__ float colPart[4][NN];
    __shared__ float sred[8];

    float4 csum = make_float4(0.f, 0.f, 0.f, 0.f);
    for (int p = wave; p < NN; p += 4) {
        float4 v = *(const float4*)(Xp + (size_t)p * NN + lane * 4);
        csum.x += v.x; csum.y += v.y; csum.z += v.z; csum.w += v.w;
        float rs = waveReduceSum(v.x + v.y + v.z + v.w);
        if (lane == 0) rowsL[p] = rs;
    }
    *(float4*)(&colPart[wave][lane * 4]) = csum;
    __syncthreads();

    float col = colPart[0][tid] + colPart[1][tid] + colPart[2][tid] + colPart[3][tid];
    const size_t gb = (size_t)bc * NN;
    cols[gb + tid] = col;
    float rsv = rowsL[tid];
    rows[gb + tid] = rsv;
    float d = Xp[(size_t)tid * (NN + 1)];
    diag[gb + tid] = d;

    float t1 = waveReduceSum(d);
    float s1 = waveReduceSum(rsv);
    if (lane == 0) { sred[wave] = t1; sred[4 + wave] = s1; }
    __syncthreads();
    if (tid == 0) {
        TSa[bc * 2 + 0] = sred[0] + sred[1] + sred[2] + sred[3];
        TSa[bc * 2 + 1] = sred[4] + sred[5] + sred[6] + sred[7];
    }
}

// ---------------- K2: P' / Q / G' per (b,o,p) ----------------
__global__ __launch_bounds__(256) void k_pqg(const float* __restrict__ W,   // 15*CIN*COUT
                                             const float* __restrict__ rows,
                                             const float* __restrict__ cols,
                                             const float* __restrict__ diag,
                                             const float* __restrict__ TSa,
                                             const float* __restrict__ bias,
                                             float* __restrict__ Pw,
                                             float* __restrict__ Qw,
                                             float* __restrict__ Gw) {
    const int bo = blockIdx.x;      // b*COUT + o
    const int b = bo / COUT, o = bo % COUT;
    const int p = threadIdx.x;

    float P = 0.f, Q = 0.f, G = 0.f, s = 0.f, gs = 0.f;
    for (int c = 0; c < CIN; ++c) {
        const size_t base = (size_t)(b * CIN + c) * NN;
        float r  = rows[base + p];
        float cl = cols[base + p];
        float dg = diag[base + p];
        const float* wp = W + c * COUT + o;
        #define WI(i) wp[(i) * CIN * COUT]
        P += WI(12) * r + WI(7)  * cl + WI(5) * dg;
        Q += WI(13) * r + WI(10) * cl + WI(9) * dg;
        G += WI(3)  * r + WI(1)  * cl + WI(0) * dg;
        float Tv = TSa[(b * CIN + c) * 2 + 0];
        float Sv = TSa[(b * CIN + c) * 2 + 1];
        s  += WI(11) * Tv + WI(14) * Sv;
        gs += WI(2)  * Tv + WI(4)  * Sv;
        #undef WI
    }
    const size_t ob = (size_t)bo * NN;
    Pw[ob + p] = P + s + bias[0];
    Qw[ob + p] = Q;
    Gw[ob + p] = G + gs;
}

// ---------------- K3: main channel-mix ----------------
// Y[b,o,p,q] = sum_c w8[c,o]*X[b,c,p,q] + sum_c w6[c,o]*X[b,c,q,p]
//            + Pw[b,o,p] + Qw[b,o,q] + (p==q)*Gw[b,o,p]
// 512 threads, 32 o-groups x 3 o's each -> acc[3][16] = 48 regs/thread, no spill.
#define BK 8
__global__ __launch_bounds__(512, 4) void k_main(const float* __restrict__ X,
                                                 const float* __restrict__ W,
                                                 const float* __restrict__ Pw,
                                                 const float* __restrict__ Qw,
                                                 const float* __restrict__ Gw,
                                                 float* __restrict__ Y) {
    // m204 bijective XCD swizzle: nwg = 16*16*4 = 1024, q = 128
    const int orig = blockIdx.x + 16 * (blockIdx.y + 16 * blockIdx.z);
    const int work = (orig % 8) * 128 + orig / 8;
    const int tq = work & 15, tp = (work >> 4) & 15, b = work >> 8;

    const int tid = threadIdx.x;
    const int to = tid >> 4, ts = tid & 15;   // o-group (3 each), pixel-row in tile

    __shared__ float XA [BK][16][20];   // direct tile, padded stride 20
    __shared__ float XBt[BK][16][20];   // transposed tile
    __shared__ float W8s[BK * 96];
    __shared__ float W6s[BK * 96];

    float acc[3][16];
    #pragma unroll
    for (int j = 0; j < 3; ++j)
        #pragma unroll
        for (int e = 0; e < 16; ++e) acc[j][e] = 0.f;

    const float* w8g = W + 8 * CIN * COUT;
    const float* w6g = W + 6 * CIN * COUT;
    const float* Xb = X + (size_t)b * CIN * NN * NN;

    // staging indices (fixed per thread): tid = cc*64 + pp*4 + jv
    const int s_cc = tid >> 6, s_r = tid & 63;
    const int s_pp = s_r >> 2, s_jv = s_r & 3;

    for (int c0 = 0; c0 < CIN; c0 += BK) {
        const float* pa = Xb + ((size_t)(c0 + s_cc) * NN + (tp * 16 + s_pp)) * NN + tq * 16 + s_jv * 4;
        float4 va = *(const float4*)pa;
        *(float4*)&XA[s_cc][s_pp][s_jv * 4] = va;
        const float* pb = Xb + ((size_t)(c0 + s_cc) * NN + (tq * 16 + s_pp)) * NN + tp * 16 + s_jv * 4;
        float4 vb = *(const float4*)pb;
        XBt[s_cc][s_jv * 4 + 0][s_pp] = vb.x;
        XBt[s_cc][s_jv * 4 + 1][s_pp] = vb.y;
        XBt[s_cc][s_jv * 4 + 2][s_pp] = vb.z;
        XBt[s_cc][s_jv * 4 + 3][s_pp] = vb.w;
        #pragma unroll
        for (int idx = tid; idx < BK * 96; idx += 512) {
            W8s[idx] = w8g[c0 * 96 + idx];
            W6s[idx] = w6g[c0 * 96 + idx];
        }
        __syncthreads();

        #pragma unroll
        for (int cc = 0; cc < BK; ++cc) {
            float w8v[3], w6v[3];
            #pragma unroll
            for (int j = 0; j < 3; ++j) {
                w8v[j] = W8s[cc * 96 + to * 3 + j];
                w6v[j] = W6s[cc * 96 + to * 3 + j];
            }
            #pragma unroll
            for (int u = 0; u < 4; ++u) {
                float4 xd = *(const float4*)&XA [cc][ts][4 * u];
                float4 xt = *(const float4*)&XBt[cc][ts][4 * u];
                #pragma unroll
                for (int j = 0; j < 3; ++j) {
                    acc[j][4 * u + 0] += w8v[j] * xd.x + w6v[j] * xt.x;
                    acc[j][4 * u + 1] += w8v[j] * xd.y + w6v[j] * xt.y;
                    acc[j][4 * u + 2] += w8v[j] * xd.z + w6v[j] * xt.z;
                    acc[j][4 * u + 3] += w8v[j] * xd.w + w6v[j] * xt.w;
                }
            }
        }
        __syncthreads();
    }

    // ---- epilogue ----
    const int p = tp * 16 + ts;
    #pragma unroll
    for (int j = 0; j < 3; ++j) {
        const int o = to * 3 + j;
        const size_t ob = (size_t)(b * COUT + o) * NN;
        float Pv = Pw[ob + p];
        float Gv = Gw[ob + p];
        const float4* qp = (const float4*)&Qw[ob + tq * 16];
        float* yp = Y + (ob + p) * NN + tq * 16;
        #pragma unroll
        for (int u = 0; u < 4; ++u) {
            float4 qv = qp[u];
            float4 out;
            out.x = acc[j][4 * u + 0] + Pv + qv.x;
            out.y = acc[j][4 * u + 1] + Pv + qv.y;
            out.z = acc[j][4 * u + 2] + Pv + qv.z;
            out.w = acc[j][4 * u + 3] + Pv + qv.w;
            if (tp == tq) {
                if (4 * u + 0 == ts) out.x += Gv;
                if (4 * u + 1 == ts) out.y += Gv;
                if (4 * u + 2 == ts) out.z += Gv;
                if (4 * u + 3 == ts) out.w += Gv;
            }
            ((float4*)yp)[u] = out;
        }
    }
}

extern "C" void kernel_launch(void* const* d_in, const int* in_sizes, int n_in,
                              void* d_out, int out_size, void* d_ws, size_t ws_size,
                              hipStream_t stream) {
    const float* X    = (const float*)d_in[0];
    // d_in[1] (Y_in) is unused by the reference
    const float* W    = (const float*)d_in[2];   // [15][96][96]
    const float* bias = (const float*)d_in[3];
    float* Y = (float*)d_out;

    float* ws   = (float*)d_ws;
    const size_t SEG = (size_t)BB * CIN * NN;    // 98304 (same for B*COUT*NN)
    float* rows = ws;
    float* cols = ws + SEG;
    float* diag = ws + 2 * SEG;
    float* Pw   = ws + 3 * SEG;
    float* Qw   = ws + 4 * SEG;
    float* Gw   = ws + 5 * SEG;
    float* TSa  = ws + 6 * SEG;                  // B*CIN*2 floats

    k_aux<<<BB * CIN, 256, 0, stream>>>(X, rows, cols, diag, TSa);
    k_pqg<<<BB * COUT, 256, 0, stream>>>(W, rows, cols, diag, TSa, bias, Pw, Qw, Gw);
    k_main<<<dim3(NN / 16, NN / 16, BB), 512, 0, stream>>>(X, W, Pw, Qw, Gw, Y);
}

// Round 3
// 328.019 us; speedup vs baseline: 7.2512x; 7.2512x over previous
//
#include <hip/hip_runtime.h>

#define NN 256
#define CIN 96
#define COUT 96
#define BB 4

__device__ __forceinline__ float waveReduceSum(float v) {
    #pragma unroll
    for (int m = 32; m >= 1; m >>= 1) v += __shfl_xor(v, m, 64);
    return v;
}

// ---------------- K1: per (b,c) rowsum / colsum / diag / T / S ----------------
__global__ __launch_bounds__(256) void k_aux(const float* __restrict__ X,
                                             float* __restrict__ rows,
                                             float* __restrict__ cols,
                                             float* __restrict__ diag,
                                             float* __restrict__ TSa) {
    const int bc = blockIdx.x;                 // 0..B*C-1
    const float* Xp = X + (size_t)bc * NN * NN;
    const int tid = threadIdx.x;
    const int wave = tid >> 6, lane = tid & 63;

    __shared__ float rowsL[NN];
    __shared__ float colPart[4][NN];
    __shared__ float sred[8];

    float4 csum = make_float4(0.f, 0.f, 0.f, 0.f);
    for (int p = wave; p < NN; p += 4) {
        float4 v = *(const float4*)(Xp + (size_t)p * NN + lane * 4);
        csum.x += v.x; csum.y += v.y; csum.z += v.z; csum.w += v.w;
        float rs = waveReduceSum(v.x + v.y + v.z + v.w);
        if (lane == 0) rowsL[p] = rs;
    }
    *(float4*)(&colPart[wave][lane * 4]) = csum;
    __syncthreads();

    float col = colPart[0][tid] + colPart[1][tid] + colPart[2][tid] + colPart[3][tid];
    const size_t gb = (size_t)bc * NN;
    cols[gb + tid] = col;
    float rsv = rowsL[tid];
    rows[gb + tid] = rsv;
    float d = Xp[(size_t)tid * (NN + 1)];
    diag[gb + tid] = d;

    float t1 = waveReduceSum(d);
    float s1 = waveReduceSum(rsv);
    if (lane == 0) { sred[wave] = t1; sred[4 + wave] = s1; }
    __syncthreads();
    if (tid == 0) {
        TSa[bc * 2 + 0] = sred[0] + sred[1] + sred[2] + sred[3];
        TSa[bc * 2 + 1] = sred[4] + sred[5] + sred[6] + sred[7];
    }
}

// ---------------- K2: P' / Q / G' per (b,o,p) ----------------
__global__ __launch_bounds__(256) void k_pqg(const float* __restrict__ W,   // 15*CIN*COUT
                                             const float* __restrict__ rows,
                                             const float* __restrict__ cols,
                                             const float* __restrict__ diag,
                                             const float* __restrict__ TSa,
                                             const float* __restrict__ bias,
                                             float* __restrict__ Pw,
                                             float* __restrict__ Qw,
                                             float* __restrict__ Gw) {
    const int bo = blockIdx.x;      // b*COUT + o
    const int b = bo / COUT, o = bo % COUT;
    const int p = threadIdx.x;

    float P = 0.f, Q = 0.f, G = 0.f, s = 0.f, gs = 0.f;
    for (int c = 0; c < CIN; ++c) {
        const size_t base = (size_t)(b * CIN + c) * NN;
        float r  = rows[base + p];
        float cl = cols[base + p];
        float dg = diag[base + p];
        const float* wp = W + c * COUT + o;
        #define WI(i) wp[(i) * CIN * COUT]
        P += WI(12) * r + WI(7)  * cl + WI(5) * dg;
        Q += WI(13) * r + WI(10) * cl + WI(9) * dg;
        G += WI(3)  * r + WI(1)  * cl + WI(0) * dg;
        float Tv = TSa[(b * CIN + c) * 2 + 0];
        float Sv = TSa[(b * CIN + c) * 2 + 1];
        s  += WI(11) * Tv + WI(14) * Sv;
        gs += WI(2)  * Tv + WI(4)  * Sv;
        #undef WI
    }
    const size_t ob = (size_t)bo * NN;
    Pw[ob + p] = P + s + bias[0];
    Qw[ob + p] = Q;
    Gw[ob + p] = G + gs;
}

// ---------------- K3: main channel-mix ----------------
// Y[b,o,p,q] = sum_c w8[c,o]*X[b,c,p,q] + sum_c w6[c,o]*X[b,c,q,p]
//            + Pw[b,o,p] + Qw[b,o,q] + (p==q)*Gw[b,o,p]
// 512 threads; thread (to,ts): o in {to*3..to*3+2}, pixels (p=tp*16+ts, q=tq*16..+15).
// Accumulators are 12 NAMED float4 vars -> cannot be demoted to scratch.
#define BK 8
#define F40 make_float4(0.f, 0.f, 0.f, 0.f)
__global__ __launch_bounds__(512, 1) void k_main(const float* __restrict__ X,
                                                 const float* __restrict__ W,
                                                 const float* __restrict__ Pw,
                                                 const float* __restrict__ Qw,
                                                 const float* __restrict__ Gw,
                                                 float* __restrict__ Y) {
    // m204 bijective XCD swizzle: nwg = 16*16*4 = 1024
    const int orig = blockIdx.x + 16 * (blockIdx.y + 16 * blockIdx.z);
    const int work = (orig % 8) * 128 + orig / 8;
    const int tq = work & 15, tp = (work >> 4) & 15, b = work >> 8;

    const int tid = threadIdx.x;
    const int to = tid >> 4, ts = tid & 15;   // o-group (3 o's each), pixel-row in tile

    __shared__ float XA [BK][16][20];   // direct tile, padded stride 20
    __shared__ float XBt[BK][16][20];   // transposed tile
    __shared__ float W8s[BK * 96];
    __shared__ float W6s[BK * 96];

    float4 a00 = F40, a01 = F40, a02 = F40, a03 = F40;
    float4 a10 = F40, a11 = F40, a12 = F40, a13 = F40;
    float4 a20 = F40, a21 = F40, a22 = F40, a23 = F40;

    const float* w8g = W + 8 * CIN * COUT;
    const float* w6g = W + 6 * CIN * COUT;
    const float* Xb = X + (size_t)b * CIN * NN * NN;

    // staging indices (fixed per thread): tid = cc*64 + pp*4 + jv
    const int s_cc = tid >> 6, s_r = tid & 63;
    const int s_pp = s_r >> 2, s_jv = s_r & 3;

    for (int c0 = 0; c0 < CIN; c0 += BK) {
        const float* pa = Xb + ((size_t)(c0 + s_cc) * NN + (tp * 16 + s_pp)) * NN + tq * 16 + s_jv * 4;
        float4 va = *(const float4*)pa;
        *(float4*)&XA[s_cc][s_pp][s_jv * 4] = va;
        const float* pb = Xb + ((size_t)(c0 + s_cc) * NN + (tq * 16 + s_pp)) * NN + tp * 16 + s_jv * 4;
        float4 vb = *(const float4*)pb;
        XBt[s_cc][s_jv * 4 + 0][s_pp] = vb.x;
        XBt[s_cc][s_jv * 4 + 1][s_pp] = vb.y;
        XBt[s_cc][s_jv * 4 + 2][s_pp] = vb.z;
        XBt[s_cc][s_jv * 4 + 3][s_pp] = vb.w;
        for (int idx = tid; idx < BK * 96; idx += 512) {
            W8s[idx] = w8g[c0 * 96 + idx];
            W6s[idx] = w6g[c0 * 96 + idx];
        }
        __syncthreads();

        #pragma unroll
        for (int cc = 0; cc < BK; ++cc) {
            const float w80 = W8s[cc * 96 + to * 3 + 0];
            const float w81 = W8s[cc * 96 + to * 3 + 1];
            const float w82 = W8s[cc * 96 + to * 3 + 2];
            const float w60 = W6s[cc * 96 + to * 3 + 0];
            const float w61 = W6s[cc * 96 + to * 3 + 1];
            const float w62 = W6s[cc * 96 + to * 3 + 2];
            #define UPD(A, W8V, W6V) \
                A.x += (W8V) * xd.x + (W6V) * xt.x; \
                A.y += (W8V) * xd.y + (W6V) * xt.y; \
                A.z += (W8V) * xd.z + (W6V) * xt.z; \
                A.w += (W8V) * xd.w + (W6V) * xt.w;
            #define STEPU(U, A0, A1, A2) { \
                float4 xd = *(const float4*)&XA [cc][ts][4 * (U)]; \
                float4 xt = *(const float4*)&XBt[cc][ts][4 * (U)]; \
                UPD(A0, w80, w60) UPD(A1, w81, w61) UPD(A2, w82, w62) }
            STEPU(0, a00, a10, a20)
            STEPU(1, a01, a11, a21)
            STEPU(2, a02, a12, a22)
            STEPU(3, a03, a13, a23)
            #undef STEPU
            #undef UPD
        }
        __syncthreads();
    }

    // ---- epilogue ----
    const int p = tp * 16 + ts;
    #define EPI(J, A0, A1, A2, A3) { \
        const int o = to * 3 + (J); \
        const size_t ob = (size_t)(b * COUT + o) * NN; \
        const float Pv = Pw[ob + p]; \
        const float Gv = Gw[ob + p]; \
        const float4* qp = (const float4*)&Qw[ob + tq * 16]; \
        float* yp = Y + (ob + p) * NN + tq * 16; \
        float4 q0 = qp[0], q1 = qp[1], q2 = qp[2], q3 = qp[3]; \
        float4 o0, o1, o2, o3; \
        o0.x = A0.x + Pv + q0.x; o0.y = A0.y + Pv + q0.y; o0.z = A0.z + Pv + q0.z; o0.w = A0.w + Pv + q0.w; \
        o1.x = A1.x + Pv + q1.x; o1.y = A1.y + Pv + q1.y; o1.z = A1.z + Pv + q1.z; o1.w = A1.w + Pv + q1.w; \
        o2.x = A2.x + Pv + q2.x; o2.y = A2.y + Pv + q2.y; o2.z = A2.z + Pv + q2.z; o2.w = A2.w + Pv + q2.w; \
        o3.x = A3.x + Pv + q3.x; o3.y = A3.y + Pv + q3.y; o3.z = A3.z + Pv + q3.z; o3.w = A3.w + Pv + q3.w; \
        if (tp == tq) { \
            float* oflat = &o0.x; \
            oflat[ts] += Gv; \
        } \
        ((float4*)yp)[0] = o0; ((float4*)yp)[1] = o1; \
        ((float4*)yp)[2] = o2; ((float4*)yp)[3] = o3; \
    }
    {
        // note: EPI's oflat trick needs o0..o3 contiguous; write them as a
        // local array ONLY inside the diagonal branch via explicit select
        // instead -- safer: use compare-select per element.
    }
    #undef EPI
    #pragma unroll
    for (int j = 0; j < 3; ++j) {
        const int o = to * 3 + j;
        const size_t ob = (size_t)(b * COUT + o) * NN;
        const float Pv = Pw[ob + p];
        const float Gv = (tp == tq) ? Gw[ob + p] : 0.f;
        const float4* qp = (const float4*)&Qw[ob + tq * 16];
        float* yp = Y + (ob + p) * NN + tq * 16;
        const float4 A0 = (j == 0) ? a00 : (j == 1) ? a10 : a20;
        const float4 A1 = (j == 0) ? a01 : (j == 1) ? a11 : a21;
        const float4 A2 = (j == 0) ? a02 : (j == 1) ? a12 : a22;
        const float4 A3 = (j == 0) ? a03 : (j == 1) ? a13 : a23;
        #pragma unroll
        for (int u = 0; u < 4; ++u) {
            const float4 A = (u == 0) ? A0 : (u == 1) ? A1 : (u == 2) ? A2 : A3;
            const float4 qv = qp[u];
            float4 out;
            out.x = A.x + Pv + qv.x + ((4 * u + 0 == ts) ? Gv : 0.f);
            out.y = A.y + Pv + qv.y + ((4 * u + 1 == ts) ? Gv : 0.f);
            out.z = A.z + Pv + qv.z + ((4 * u + 2 == ts) ? Gv : 0.f);
            out.w = A.w + Pv + qv.w + ((4 * u + 3 == ts) ? Gv : 0.f);
            ((float4*)yp)[u] = out;
        }
    }
}

extern "C" void kernel_launch(void* const* d_in, const int* in_sizes, int n_in,
                              void* d_out, int out_size, void* d_ws, size_t ws_size,
                              hipStream_t stream) {
    const float* X    = (const float*)d_in[0];
    // d_in[1] (Y_in) is unused by the reference
    const float* W    = (const float*)d_in[2];   // [15][96][96]
    const float* bias = (const float*)d_in[3];
    float* Y = (float*)d_out;

    float* ws   = (float*)d_ws;
    const size_t SEG = (size_t)BB * CIN * NN;    // 98304 (same for B*COUT*NN)
    float* rows = ws;
    float* cols = ws + SEG;
    float* diag = ws + 2 * SEG;
    float* Pw   = ws + 3 * SEG;
    float* Qw   = ws + 4 * SEG;
    float* Gw   = ws + 5 * SEG;
    float* TSa  = ws + 6 * SEG;                  // B*CIN*2 floats

    k_aux<<<BB * CIN, 256, 0, stream>>>(X, rows, cols, diag, TSa);
    k_pqg<<<BB * COUT, 256, 0, stream>>>(W, rows, cols, diag, TSa, bias, Pw, Qw, Gw);
    k_main<<<dim3(NN / 16, NN / 16, BB), 512, 0, stream>>>(X, W, Pw, Qw, Gw, Y);
}

// Round 4
// 141.100 us; speedup vs baseline: 16.8571x; 2.3247x over previous
//
#include <hip/hip_runtime.h>
#include <hip/hip_bf16.h>

#define NN 256
#define CIN 96
#define COUT 96
#define BB 4

typedef __attribute__((ext_vector_type(8))) short short8;
typedef __attribute__((ext_vector_type(4))) float f32x4;

__device__ __forceinline__ float waveReduceSum(float v) {
    #pragma unroll
    for (int m = 32; m >= 1; m >>= 1) v += __shfl_xor(v, m, 64);
    return v;
}

__device__ __forceinline__ unsigned int packbf2(float lo, float hi) {
    __hip_bfloat162 h = __float22bfloat162_rn(make_float2(lo, hi));
    unsigned int u;
    __builtin_memcpy(&u, &h, 4);
    return u;
}

// ---------------- K1: per (b,c) rowsum / colsum / diag / T / S ----------------
__global__ __launch_bounds__(256) void k_aux(const float* __restrict__ X,
                                             float* __restrict__ rows,
                                             float* __restrict__ cols,
                                             float* __restrict__ diag,
                                             float* __restrict__ TSa) {
    const int bc = blockIdx.x;
    const float* Xp = X + (size_t)bc * NN * NN;
    const int tid = threadIdx.x;
    const int wave = tid >> 6, lane = tid & 63;

    __shared__ float rowsL[NN];
    __shared__ float colPart[4][NN];
    __shared__ float sred[8];

    float4 csum = make_float4(0.f, 0.f, 0.f, 0.f);
    for (int p = wave; p < NN; p += 4) {
        float4 v = *(const float4*)(Xp + (size_t)p * NN + lane * 4);
        csum.x += v.x; csum.y += v.y; csum.z += v.z; csum.w += v.w;
        float rs = waveReduceSum(v.x + v.y + v.z + v.w);
        if (lane == 0) rowsL[p] = rs;
    }
    *(float4*)(&colPart[wave][lane * 4]) = csum;
    __syncthreads();

    float col = colPart[0][tid] + colPart[1][tid] + colPart[2][tid] + colPart[3][tid];
    const size_t gb = (size_t)bc * NN;
    cols[gb + tid] = col;
    float rsv = rowsL[tid];
    rows[gb + tid] = rsv;
    float d = Xp[(size_t)tid * (NN + 1)];
    diag[gb + tid] = d;

    float t1 = waveReduceSum(d);
    float s1 = waveReduceSum(rsv);
    if (lane == 0) { sred[wave] = t1; sred[4 + wave] = s1; }
    __syncthreads();
    if (tid == 0) {
        TSa[bc * 2 + 0] = sred[0] + sred[1] + sred[2] + sred[3];
        TSa[bc * 2 + 1] = sred[4] + sred[5] + sred[6] + sred[7];
    }
}

// ---------------- K2: P' / Q / G' per (b,o,p) ----------------
__global__ __launch_bounds__(256) void k_pqg(const float* __restrict__ W,
                                             const float* __restrict__ rows,
                                             const float* __restrict__ cols,
                                             const float* __restrict__ diag,
                                             const float* __restrict__ TSa,
                                             const float* __restrict__ bias,
                                             float* __restrict__ Pw,
                                             float* __restrict__ Qw,
                                             float* __restrict__ Gw) {
    const int bo = blockIdx.x;
    const int b = bo / COUT, o = bo % COUT;
    const int p = threadIdx.x;

    float P = 0.f, Q = 0.f, G = 0.f, s = 0.f, gs = 0.f;
    for (int c = 0; c < CIN; ++c) {
        const size_t base = (size_t)(b * CIN + c) * NN;
        float r  = rows[base + p];
        float cl = cols[base + p];
        float dg = diag[base + p];
        const float* wp = W + c * COUT + o;
        #define WI(i) wp[(i) * CIN * COUT]
        P += WI(12) * r + WI(7)  * cl + WI(5) * dg;
        Q += WI(13) * r + WI(10) * cl + WI(9) * dg;
        G += WI(3)  * r + WI(1)  * cl + WI(0) * dg;
        float Tv = TSa[(b * CIN + c) * 2 + 0];
        float Sv = TSa[(b * CIN + c) * 2 + 1];
        s  += WI(11) * Tv + WI(14) * Sv;
        gs += WI(2)  * Tv + WI(4)  * Sv;
        #undef WI
    }
    const size_t ob = (size_t)bo * NN;
    Pw[ob + p] = P + s + bias[0];
    Qw[ob + p] = Q;
    Gw[ob + p] = G + gs;
}

// ---------------- K3: MFMA channel-mix ----------------
// Y[b,o,p,q] = sum_c w8[c,o]*X[b,c,p,q] + sum_c w6[c,o]*X[b,c,q,p]
//            + Pw[b,o,p] + Qw[b,o,q] + (p==q)*Gw[b,o,p]
// Per block: 16x16 spatial tile, all 96 o. mfma_f32_16x16x32_bf16:
// M=o-tile(6), N=q within p-row (16 p-rows), K=c (3 ksteps of 32).
// LDS X layout [p][17 q-slots][40 bf16 c], c stored K-SPLIT-permuted so one
// ds_read_b128 = full B-frag: pos(c) = 8*((c&15)>>2) + 4*(c>>4) + (c&3).
#define XSTRIDE 20            /* uint words per q-slot (40 bf16: 32 data + pad) */
#define XROW    (17 * XSTRIDE)
#define WSTRIDE 20

__device__ __forceinline__ int permw(int cw) {   // word-level perm of pos(c)
    return ((cw & 6) << 1) | ((cw & 8) >> 2) | (cw & 1);
}

__global__ __launch_bounds__(512, 1) void k_main(const float* __restrict__ X,
                                                 const float* __restrict__ W,
                                                 const float* __restrict__ Pw,
                                                 const float* __restrict__ Qw,
                                                 const float* __restrict__ Gw,
                                                 float* __restrict__ Y) {
    __shared__ __align__(16) unsigned int XAs[16 * XROW];   // [p][q][cperm] direct tile
    __shared__ __align__(16) unsigned int XBs[16 * XROW];   // [r][q][cperm] transposed tile
    __shared__ __align__(16) unsigned int W8s[96 * WSTRIDE];
    __shared__ __align__(16) unsigned int W6s[96 * WSTRIDE];

    // bijective XCD swizzle (nwg = 1024, 1024 % 8 == 0)
    const int orig = blockIdx.x + 16 * (blockIdx.y + 16 * blockIdx.z);
    const int work = (orig & 7) * 128 + (orig >> 3);
    const int tq = work & 15, tp = (work >> 4) & 15, b = work >> 8;

    const int tid = threadIdx.x;
    const int w = tid >> 6, lane = tid & 63;

    // staging: lane -> (row sp, col-quad sq4); wave -> 4 channels
    const int sp = lane >> 2, sq4 = (lane & 3) * 4;
    // compute: lane -> (col, k-group)
    const int col = lane & 15, g = lane >> 4;
    const int r0 = w, r1 = w + 8;

    f32x4 acc[6][2];
    #pragma unroll
    for (int m = 0; m < 6; ++m) {
        acc[m][0] = f32x4{0.f, 0.f, 0.f, 0.f};
        acc[m][1] = f32x4{0.f, 0.f, 0.f, 0.f};
    }

    const float* Xb  = X + (size_t)b * CIN * NN * NN;
    const float* G1  = Xb + (size_t)(tp * 16) * NN + tq * 16;
    const float* G2  = Xb + (size_t)(tq * 16) * NN + tp * 16;
    const float* w8g = W + 8 * CIN * COUT;
    const float* w6g = W + 6 * CIN * COUT;

    for (int c0 = 0; c0 < CIN; c0 += 32) {
        __syncthreads();   // previous iter's frag reads done before overwrite

        // ---- stage X tiles (fp32 -> bf16 pairs) ----
        #pragma unroll
        for (int h = 0; h < 2; ++h) {
            const int c   = 4 * w + 2 * h;            // local channel (even)
            const int cwp = permw(2 * w + h);
            const float* pa = G1 + (size_t)(c0 + c) * (NN * NN) + sp * NN + sq4;
            float4 a0 = *(const float4*)pa;
            float4 a1 = *(const float4*)(pa + NN * NN);
            unsigned int* dstA = &XAs[(sp * 17 + sq4) * XSTRIDE + cwp];
            dstA[0 * XSTRIDE] = packbf2(a0.x, a1.x);
            dstA[1 * XSTRIDE] = packbf2(a0.y, a1.y);
            dstA[2 * XSTRIDE] = packbf2(a0.z, a1.z);
            dstA[3 * XSTRIDE] = packbf2(a0.w, a1.w);
            const float* pb = G2 + (size_t)(c0 + c) * (NN * NN) + sp * NN + sq4;
            float4 b0 = *(const float4*)pb;
            float4 b1 = *(const float4*)(pb + NN * NN);
            unsigned int* dstB = &XBs[(sq4 * 17 + sp) * XSTRIDE + cwp];
            dstB[0 * 17 * XSTRIDE] = packbf2(b0.x, b1.x);
            dstB[1 * 17 * XSTRIDE] = packbf2(b0.y, b1.y);
            dstB[2 * 17 * XSTRIDE] = packbf2(b0.z, b1.z);
            dstB[3 * 17 * XSTRIDE] = packbf2(b0.w, b1.w);
        }
        // ---- stage weight slices (transposed, bf16 pairs) ----
        #pragma unroll
        for (int it = 0; it < 3; ++it) {
            const int i  = tid + it * 512;        // 0..1535
            const int cp = i / 96;                // c-pair 0..15
            const int o  = i - cp * 96;
            const int cwp = permw(cp);
            W8s[o * WSTRIDE + cwp] =
                packbf2(w8g[(c0 + 2 * cp) * COUT + o], w8g[(c0 + 2 * cp + 1) * COUT + o]);
            W6s[o * WSTRIDE + cwp] =
                packbf2(w6g[(c0 + 2 * cp) * COUT + o], w6g[(c0 + 2 * cp + 1) * COUT + o]);
        }
        __syncthreads();

        // ---- compute: 24 MFMA per wave per kstep ----
        short8 xd0 = *(const short8*)&XAs[(r0 * 17 + col) * XSTRIDE + g * 4];
        short8 xd1 = *(const short8*)&XAs[(r1 * 17 + col) * XSTRIDE + g * 4];
        short8 xt0 = *(const short8*)&XBs[(r0 * 17 + col) * XSTRIDE + g * 4];
        short8 xt1 = *(const short8*)&XBs[(r1 * 17 + col) * XSTRIDE + g * 4];
        #pragma unroll
        for (int m = 0; m < 6; ++m) {
            short8 a8 = *(const short8*)&W8s[(m * 16 + col) * WSTRIDE + g * 4];
            short8 a6 = *(const short8*)&W6s[(m * 16 + col) * WSTRIDE + g * 4];
            acc[m][0] = __builtin_amdgcn_mfma_f32_16x16x32_bf16(a8, xd0, acc[m][0], 0, 0, 0);
            acc[m][0] = __builtin_amdgcn_mfma_f32_16x16x32_bf16(a6, xt0, acc[m][0], 0, 0, 0);
            acc[m][1] = __builtin_amdgcn_mfma_f32_16x16x32_bf16(a8, xd1, acc[m][1], 0, 0, 0);
            acc[m][1] = __builtin_amdgcn_mfma_f32_16x16x32_bf16(a6, xt1, acc[m][1], 0, 0, 0);
        }
    }

    // ---- epilogue: fp32 P/Q/diag-G + store ----
    #pragma unroll
    for (int rr = 0; rr < 2; ++rr) {
        const int r = w + rr * 8;
        const int p = tp * 16 + r;
        const int q = tq * 16 + col;
        const bool dg = (tp == tq) && (col == r);
        #pragma unroll
        for (int m = 0; m < 6; ++m) {
            #pragma unroll
            for (int i = 0; i < 4; ++i) {
                const int o = m * 16 + g * 4 + i;
                const size_t ob = (size_t)(b * COUT + o) * NN;
                float v = acc[m][rr][i] + Pw[ob + p] + Qw[ob + q];
                if (dg) v += Gw[ob + p];
                Y[(ob + p) * NN + q] = v;
            }
        }
    }
}

extern "C" void kernel_launch(void* const* d_in, const int* in_sizes, int n_in,
                              void* d_out, int out_size, void* d_ws, size_t ws_size,
                              hipStream_t stream) {
    const float* X    = (const float*)d_in[0];
    const float* W    = (const float*)d_in[2];   // [15][96][96]
    const float* bias = (const float*)d_in[3];
    float* Y = (float*)d_out;

    float* ws   = (float*)d_ws;
    const size_t SEG = (size_t)BB * CIN * NN;    // 98304
    float* rows = ws;
    float* cols = ws + SEG;
    float* diag = ws + 2 * SEG;
    float* Pw   = ws + 3 * SEG;
    float* Qw   = ws + 4 * SEG;
    float* Gw   = ws + 5 * SEG;
    float* TSa  = ws + 6 * SEG;

    k_aux<<<BB * CIN, 256, 0, stream>>>(X, rows, cols, diag, TSa);
    k_pqg<<<BB * COUT, 256, 0, stream>>>(W, rows, cols, diag, TSa, bias, Pw, Qw, Gw);
    k_main<<<dim3(16, 16, BB), 512, 0, stream>>>(X, W, Pw, Qw, Gw, Y);
}

// Round 5
// 124.013 us; speedup vs baseline: 19.1798x; 1.1378x over previous
//
#include <hip/hip_runtime.h>
#include <hip/hip_bf16.h>

#define NN 256
#define CIN 96
#define COUT 96
#define BB 4

typedef __attribute__((ext_vector_type(8))) short short8;
typedef __attribute__((ext_vector_type(4))) float f32x4;

__device__ __forceinline__ float waveReduceSum(float v) {
    #pragma unroll
    for (int m = 32; m >= 1; m >>= 1) v += __shfl_xor(v, m, 64);
    return v;
}

__device__ __forceinline__ unsigned int packbf2(float lo, float hi) {
    __hip_bfloat162 h = __float22bfloat162_rn(make_float2(lo, hi));
    unsigned int u;
    __builtin_memcpy(&u, &h, 4);
    return u;
}

__device__ __forceinline__ short8 u4_to_s8(uint4 u) {
    short8 r;
    __builtin_memcpy(&r, &u, 16);
    return r;
}

// ---------------- K1: per (b,c) rowsum / colsum / diag / T / S ----------------
__global__ __launch_bounds__(256) void k_aux(const float* __restrict__ X,
                                             float* __restrict__ rows,
                                             float* __restrict__ cols,
                                             float* __restrict__ diag,
                                             float* __restrict__ TSa) {
    const int bc = blockIdx.x;
    const float* Xp = X + (size_t)bc * NN * NN;
    const int tid = threadIdx.x;
    const int wave = tid >> 6, lane = tid & 63;

    __shared__ float rowsL[NN];
    __shared__ float colPart[4][NN];
    __shared__ float sred[8];

    float4 csum = make_float4(0.f, 0.f, 0.f, 0.f);
    for (int p = wave; p < NN; p += 4) {
        float4 v = *(const float4*)(Xp + (size_t)p * NN + lane * 4);
        csum.x += v.x; csum.y += v.y; csum.z += v.z; csum.w += v.w;
        float rs = waveReduceSum(v.x + v.y + v.z + v.w);
        if (lane == 0) rowsL[p] = rs;
    }
    *(float4*)(&colPart[wave][lane * 4]) = csum;
    __syncthreads();

    float col = colPart[0][tid] + colPart[1][tid] + colPart[2][tid] + colPart[3][tid];
    const size_t gb = (size_t)bc * NN;
    cols[gb + tid] = col;
    float rsv = rowsL[tid];
    rows[gb + tid] = rsv;
    float d = Xp[(size_t)tid * (NN + 1)];
    diag[gb + tid] = d;

    float t1 = waveReduceSum(d);
    float s1 = waveReduceSum(rsv);
    if (lane == 0) { sred[wave] = t1; sred[4 + wave] = s1; }
    __syncthreads();
    if (tid == 0) {
        TSa[bc * 2 + 0] = sred[0] + sred[1] + sred[2] + sred[3];
        TSa[bc * 2 + 1] = sred[4] + sred[5] + sred[6] + sred[7];
    }
}

// ---------------- K2: P' / Q / G' per (b,o,p), c-split x2 ----------------
__global__ __launch_bounds__(512) void k_pqg(const float* __restrict__ W,
                                             const float* __restrict__ rows,
                                             const float* __restrict__ cols,
                                             const float* __restrict__ diag,
                                             const float* __restrict__ TSa,
                                             const float* __restrict__ bias,
                                             float* __restrict__ Pw,
                                             float* __restrict__ Qw,
                                             float* __restrict__ Gw) {
    const int bo = blockIdx.x;
    const int b = bo / COUT, o = bo % COUT;
    const int half = threadIdx.x >> 8;
    const int p = threadIdx.x & 255;

    __shared__ float red[5][256];

    float P = 0.f, Q = 0.f, G = 0.f, s = 0.f, gs = 0.f;
    const int cbeg = half * 48, cend = cbeg + 48;
    for (int c = cbeg; c < cend; ++c) {
        const size_t base = (size_t)(b * CIN + c) * NN;
        float r  = rows[base + p];
        float cl = cols[base + p];
        float dg = diag[base + p];
        const float* wp = W + c * COUT + o;
        #define WI(i) wp[(i) * CIN * COUT]
        P += WI(12) * r + WI(7)  * cl + WI(5) * dg;
        Q += WI(13) * r + WI(10) * cl + WI(9) * dg;
        G += WI(3)  * r + WI(1)  * cl + WI(0) * dg;
        float Tv = TSa[(b * CIN + c) * 2 + 0];
        float Sv = TSa[(b * CIN + c) * 2 + 1];
        s  += WI(11) * Tv + WI(14) * Sv;
        gs += WI(2)  * Tv + WI(4)  * Sv;
        #undef WI
    }
    if (half == 1) {
        red[0][p] = P; red[1][p] = Q; red[2][p] = G; red[3][p] = s; red[4][p] = gs;
    }
    __syncthreads();
    if (half == 0) {
        P += red[0][p]; Q += red[1][p]; G += red[2][p]; s += red[3][p]; gs += red[4][p];
        const size_t ob = (size_t)bo * NN;
        Pw[ob + p] = P + s + bias[0];
        Qw[ob + p] = Q;
        Gw[ob + p] = G + gs;
    }
}

// ---------------- K3: MFMA channel-mix, conflict-free LDS ----------------
// Y[b,o,p,q] = sum_c w8[c,o]*X[b,c,p,q] + sum_c w6[c,o]*X[b,c,q,p]
//            + Pw[b,o,p] + Qw[b,o,q] + (p==q)*Gw[b,o,p]
// LDS X: c-major [cw-plane][p][q], plane stride 324 words (324%32=4 spreads
// frag-read words across banks), row stride 20. XA staged via b128 writes
// (bank-ideal), XB transposed via 4x b32 (2-way = free). All frag reads <=2-way.
// MFMA operands: D[q, o] = Xfrag (A, M=q) * Wfrag (B, N=o) -> lane holds
// q-quad at fixed o => float4 epilogue stores.
#define XPLANE 324
#define WPLANE 100

__global__ __launch_bounds__(512, 1) void k_main(const float* __restrict__ X,
                                                 const float* __restrict__ W,
                                                 const float* __restrict__ Pw,
                                                 const float* __restrict__ Qw,
                                                 const float* __restrict__ Gw,
                                                 float* __restrict__ Y) {
    __shared__ __align__(16) unsigned int XAs[16 * XPLANE];
    __shared__ __align__(16) unsigned int XBs[16 * XPLANE];
    __shared__ __align__(16) unsigned int W8s[16 * WPLANE];
    __shared__ __align__(16) unsigned int W6s[16 * WPLANE];

    // bijective XCD swizzle (nwg = 1024)
    const int orig = blockIdx.x + 16 * (blockIdx.y + 16 * blockIdx.z);
    const int work = (orig & 7) * 128 + (orig >> 3);
    const int tq = work & 15, tp = (work >> 4) & 15, b = work >> 8;

    const int tid = threadIdx.x;
    const int w = tid >> 6, lane = tid & 63;
    const int sp = lane >> 2, sq4 = (lane & 3) * 4;   // staging: row, q-quad
    const int col = lane & 15, g = lane >> 4;         // compute: o-low / q-quad idx

    f32x4 acc[6][2];
    #pragma unroll
    for (int m = 0; m < 6; ++m) {
        acc[m][0] = f32x4{0.f, 0.f, 0.f, 0.f};
        acc[m][1] = f32x4{0.f, 0.f, 0.f, 0.f};
    }

    const float* Xb  = X + (size_t)b * CIN * NN * NN;
    const float* G1  = Xb + (size_t)(tp * 16) * NN + tq * 16;
    const float* G2  = Xb + (size_t)(tq * 16) * NN + tp * 16;
    const float* w8g = W + 8 * CIN * COUT;
    const float* w6g = W + 6 * CIN * COUT;

    for (int c0 = 0; c0 < CIN; c0 += 32) {
        __syncthreads();

        // ---- stage X: wave w handles cw in {w, w+8}; cw = channel pair ----
        #pragma unroll
        for (int h = 0; h < 2; ++h) {
            const int cw = w + 8 * h;
            const size_t cb = (size_t)(c0 + 2 * cw) * (NN * NN);
            const float* pa = G1 + cb + sp * NN + sq4;
            float4 a0 = *(const float4*)pa;
            float4 a1 = *(const float4*)(pa + NN * NN);
            uint4 pk;
            pk.x = packbf2(a0.x, a1.x);
            pk.y = packbf2(a0.y, a1.y);
            pk.z = packbf2(a0.z, a1.z);
            pk.w = packbf2(a0.w, a1.w);
            *(uint4*)&XAs[cw * XPLANE + sp * 20 + sq4] = pk;      // b128, bank-ideal

            const float* pb = G2 + cb + sp * NN + sq4;
            float4 b0 = *(const float4*)pb;
            float4 b1 = *(const float4*)(pb + NN * NN);
            unsigned int* dB = &XBs[cw * XPLANE + sp];            // transposed: [q'][p']
            dB[(sq4 + 0) * 20] = packbf2(b0.x, b1.x);
            dB[(sq4 + 1) * 20] = packbf2(b0.y, b1.y);
            dB[(sq4 + 2) * 20] = packbf2(b0.z, b1.z);
            dB[(sq4 + 3) * 20] = packbf2(b0.w, b1.w);
        }
        // ---- stage weights: [cw][o] ----
        #pragma unroll
        for (int it = 0; it < 3; ++it) {
            const int i  = tid + it * 512;     // 0..1535 = cw*96 + o
            const int cw = i / 96, o = i - cw * 96;
            const int cg = (c0 + 2 * cw) * COUT + o;
            W8s[cw * WPLANE + o] = packbf2(w8g[cg], w8g[cg + COUT]);
            W6s[cw * WPLANE + o] = packbf2(w6g[cg], w6g[cg + COUT]);
        }
        __syncthreads();

        // ---- frags: words j at plane 4g+j; rows r0=w, r1=w+8 ----
        const unsigned int* xab = &XAs[4 * g * XPLANE + w * 20 + col];
        const unsigned int* xbb = &XBs[4 * g * XPLANE + w * 20 + col];
        uint4 u;
        u.x = xab[0]; u.y = xab[XPLANE]; u.z = xab[2 * XPLANE]; u.w = xab[3 * XPLANE];
        short8 xd0 = u4_to_s8(u);
        u.x = xab[160]; u.y = xab[XPLANE + 160]; u.z = xab[2 * XPLANE + 160]; u.w = xab[3 * XPLANE + 160];
        short8 xd1 = u4_to_s8(u);
        u.x = xbb[0]; u.y = xbb[XPLANE]; u.z = xbb[2 * XPLANE]; u.w = xbb[3 * XPLANE];
        short8 xt0 = u4_to_s8(u);
        u.x = xbb[160]; u.y = xbb[XPLANE + 160]; u.z = xbb[2 * XPLANE + 160]; u.w = xbb[3 * XPLANE + 160];
        short8 xt1 = u4_to_s8(u);

        #pragma unroll
        for (int m = 0; m < 6; ++m) {
            const unsigned int* wp8 = &W8s[4 * g * WPLANE + m * 16 + col];
            const unsigned int* wp6 = &W6s[4 * g * WPLANE + m * 16 + col];
            uint4 v8, v6;
            v8.x = wp8[0]; v8.y = wp8[WPLANE]; v8.z = wp8[2 * WPLANE]; v8.w = wp8[3 * WPLANE];
            v6.x = wp6[0]; v6.y = wp6[WPLANE]; v6.z = wp6[2 * WPLANE]; v6.w = wp6[3 * WPLANE];
            short8 w8f = u4_to_s8(v8);
            short8 w6f = u4_to_s8(v6);
            acc[m][0] = __builtin_amdgcn_mfma_f32_16x16x32_bf16(xd0, w8f, acc[m][0], 0, 0, 0);
            acc[m][0] = __builtin_amdgcn_mfma_f32_16x16x32_bf16(xt0, w6f, acc[m][0], 0, 0, 0);
            acc[m][1] = __builtin_amdgcn_mfma_f32_16x16x32_bf16(xd1, w8f, acc[m][1], 0, 0, 0);
            acc[m][1] = __builtin_amdgcn_mfma_f32_16x16x32_bf16(xt1, w6f, acc[m][1], 0, 0, 0);
        }
    }

    // ---- epilogue: lane holds q-quad (q4 = tq*16+g*4) at o = m*16+col ----
    const int p0 = tp * 16 + w;
    const int q4 = tq * 16 + g * 4;
    const bool diagblk = (tp == tq);
    #pragma unroll
    for (int m = 0; m < 6; ++m) {
        const int o = m * 16 + col;
        const size_t ob = (size_t)(b * COUT + o) * NN;
        const float4 qf = *(const float4*)&Qw[ob + q4];
        #pragma unroll
        for (int rr = 0; rr < 2; ++rr) {
            const int p = p0 + rr * 8;
            const float pv = Pw[ob + p];
            float4 out;
            out.x = acc[m][rr][0] + pv + qf.x;
            out.y = acc[m][rr][1] + pv + qf.y;
            out.z = acc[m][rr][2] + pv + qf.z;
            out.w = acc[m][rr][3] + pv + qf.w;
            if (diagblk) {
                const float gv = Gw[ob + p];
                const int d = (p & 15) - g * 4;
                if (d == 0) out.x += gv;
                else if (d == 1) out.y += gv;
                else if (d == 2) out.z += gv;
                else if (d == 3) out.w += gv;
            }
            *(float4*)&Y[(ob + p) * NN + q4] = out;
        }
    }
}

extern "C" void kernel_launch(void* const* d_in, const int* in_sizes, int n_in,
                              void* d_out, int out_size, void* d_ws, size_t ws_size,
                              hipStream_t stream) {
    const float* X    = (const float*)d_in[0];
    const float* W    = (const float*)d_in[2];   // [15][96][96]
    const float* bias = (const float*)d_in[3];
    float* Y = (float*)d_out;

    float* ws   = (float*)d_ws;
    const size_t SEG = (size_t)BB * CIN * NN;    // 98304
    float* rows = ws;
    float* cols = ws + SEG;
    float* diag = ws + 2 * SEG;
    float* Pw   = ws + 3 * SEG;
    float* Qw   = ws + 4 * SEG;
    float* Gw   = ws + 5 * SEG;
    float* TSa  = ws + 6 * SEG;

    k_aux<<<BB * CIN, 256, 0, stream>>>(X, rows, cols, diag, TSa);
    k_pqg<<<BB * COUT, 512, 0, stream>>>(W, rows, cols, diag, TSa, bias, Pw, Qw, Gw);
    k_main<<<dim3(16, 16, BB), 512, 0, stream>>>(X, W, Pw, Qw, Gw, Y);
}